// Round 2
// baseline (95.319 us; speedup 1.0000x reference)
//
#include <hip/hip_runtime.h>
#include <math.h>

// y[t, j] = (t/n) * a3[j] + b3[j]
//   a  = W1eff[:, 0]                (128)    b  = W1eff[:, 1:] @ X   (128)
//   a2 = W2eff @ a                  (32)     b2 = W2eff @ b          (32)
//   a3 = W3eff @ a2                 (32)     b3 = W3eff @ b2         (32)
// ws float layout: a[0:128], b[128:256], a2[256:288], b2[288:320],
//                  a3[320:352], b3[352:384]

__device__ __forceinline__ float nac_w(float wh, float mh) {
    return tanhf(wh) * (1.0f / (1.0f + __expf(-mh)));
}

// 128 blocks (one per row of W1), 512 threads (one per column).
__global__ void fp_stage1(const float* __restrict__ X,
                          const float* __restrict__ W1,
                          const float* __restrict__ M1,
                          float* __restrict__ ws) {
    const int k = blockIdx.x;      // row 0..127
    const int j = threadIdx.x;     // col 0..511
    const int idx = k * 512 + j;
    float w = nac_w(W1[idx], M1[idx]);
    float xv = (j == 0) ? 0.0f : X[j - 1];
    float p = w * xv;
    #pragma unroll
    for (int m = 32; m >= 1; m >>= 1) p += __shfl_xor(p, m, 64);
    __shared__ float red[8];
    const int wave = j >> 6;
    if ((j & 63) == 0) red[wave] = p;
    __syncthreads();
    if (j == 0) {
        float bsum = 0.0f;
        #pragma unroll
        for (int w8 = 0; w8 < 8; ++w8) bsum += red[w8];
        ws[k] = w;            // a[k] = eff weight at column 0 (thread j==0 holds it)
        ws[128 + k] = bsum;   // b[k]
    }
}

// 1 block, 256 threads (4 waves).
__global__ void fp_stage2(const float* __restrict__ W2,
                          const float* __restrict__ M2,
                          const float* __restrict__ W3,
                          const float* __restrict__ M3,
                          float* __restrict__ ws) {
    const int tid = threadIdx.x;
    const int wave = tid >> 6;
    const int lane = tid & 63;
    const float* a = ws;
    const float* b = ws + 128;

    // Phase A: a2/b2 = W2eff @ {a,b}.  Wave w handles rows w*8 .. w*8+7.
    #pragma unroll
    for (int r = 0; r < 8; ++r) {
        const int k = wave * 8 + r;
        float w0 = nac_w(W2[k * 128 + lane],      M2[k * 128 + lane]);
        float w1 = nac_w(W2[k * 128 + 64 + lane], M2[k * 128 + 64 + lane]);
        float pa = w0 * a[lane] + w1 * a[64 + lane];
        float pb = w0 * b[lane] + w1 * b[64 + lane];
        #pragma unroll
        for (int m = 32; m >= 1; m >>= 1) {
            pa += __shfl_xor(pa, m, 64);
            pb += __shfl_xor(pb, m, 64);
        }
        if (lane == 0) { ws[256 + k] = pa; ws[288 + k] = pb; }
    }
    __syncthreads();

    // Phase B: a3/b3 = W3eff @ {a2,b2}.  32x32; both 32-lane halves redundant.
    const float* a2 = ws + 256;
    const float* b2 = ws + 288;
    const int col = lane & 31;
    #pragma unroll
    for (int r = 0; r < 8; ++r) {
        const int row = wave * 8 + r;
        float w = nac_w(W3[row * 32 + col], M3[row * 32 + col]);
        float pa = w * a2[col];
        float pb = w * b2[col];
        #pragma unroll
        for (int m = 16; m >= 1; m >>= 1) {
            pa += __shfl_xor(pa, m, 32);
            pb += __shfl_xor(pb, m, 32);
        }
        if (lane == 0) { ws[320 + row] = pa; ws[352 + row] = pb; }
    }
}

// Streaming writer: out[t*32 + j] = fma(t*inv_n, a3[j], b3[j]); float4 stores.
__global__ void fp_writer(const float* __restrict__ coef,  // a3 at [0:32], b3 at [32:64]
                          float* __restrict__ out,
                          int T, float inv_n) {
    __shared__ float sA[32], sB[32];
    const int tid = threadIdx.x;
    if (tid < 32) { sA[tid] = coef[tid]; sB[tid] = coef[32 + tid]; }
    __syncthreads();

    const int total = T * 8;                       // float4 groups (32 floats/row)
    const int stride = gridDim.x * blockDim.x;     // multiple of 8 (blockDim=256)
    int idx = blockIdx.x * blockDim.x + tid;
    if (idx >= total) return;
    // idx % 8 is invariant across grid-stride iterations -> hoist coef reads.
    const int g = idx & 7;
    const int j = g * 4;
    const float a0 = sA[j], a1 = sA[j + 1], a2 = sA[j + 2], a3 = sA[j + 3];
    const float b0 = sB[j], b1 = sB[j + 1], b2 = sB[j + 2], b3 = sB[j + 3];
    float4* __restrict__ out4 = reinterpret_cast<float4*>(out);
    for (; idx < total; idx += stride) {
        const float tv = (float)(idx >> 3) * inv_n;
        float4 o;
        o.x = fmaf(tv, a0, b0);
        o.y = fmaf(tv, a1, b1);
        o.z = fmaf(tv, a2, b2);
        o.w = fmaf(tv, a3, b3);
        out4[idx] = o;
    }
}

extern "C" void kernel_launch(void* const* d_in, const int* in_sizes, int n_in,
                              void* d_out, int out_size, void* d_ws, size_t ws_size,
                              hipStream_t stream) {
    const float* X  = (const float*)d_in[0];
    const float* W1 = (const float*)d_in[1];
    const float* M1 = (const float*)d_in[2];
    const float* W2 = (const float*)d_in[3];
    const float* M2 = (const float*)d_in[4];
    const float* W3 = (const float*)d_in[5];
    const float* M3 = (const float*)d_in[6];
    float* out = (float*)d_out;
    float* ws  = (float*)d_ws;

    const int T = out_size / 32;                 // == n_steps (262144)
    const float inv_n = 1.0f / (float)T;         // T = 2^18, exact

    fp_stage1<<<128, 512, 0, stream>>>(X, W1, M1, ws);
    fp_stage2<<<1, 256, 0, stream>>>(W2, M2, W3, M3, ws);

    const int total = T * 8;
    int blocks = (total + 255) / 256;
    if (blocks > 2048) blocks = 2048;
    fp_writer<<<blocks, 256, 0, stream>>>(ws + 320, out, T, inv_n);
}